// Round 13
// baseline (38.134 us; speedup 1.0000x reference)
//
#include <hip/hip_runtime.h>
#include <stdint.h>

// HeteNet distribute_compute: T=64, N=64, D=512, H=512, A=32, E=15
// SINGLE self-contained kernel: per-block dispatch from pick, W read as fp32
// directly from global (cvt to bf16 fragments in-register), direct out stores.
#define NTOK 4096
#define DDIM 512
#define HDIM 512
#define ADIM 32
#define NEXP 15
#define TILE_M 32
#define GRID_F 144     // >= max ntiles (4096/32 + 15 partials = 143)

typedef __attribute__((ext_vector_type(8))) short bf16x8;
typedef __attribute__((ext_vector_type(8))) unsigned short ushort8;
typedef __attribute__((ext_vector_type(4))) float f32x4;

__device__ __forceinline__ unsigned short f2bf(float f) {
  unsigned int u = __float_as_uint(f);
  u += 0x7fffu + ((u >> 16) & 1u);   // round-to-nearest-even
  return (unsigned short)(u >> 16);
}

__device__ __forceinline__ bf16x8 pack8(const float* w) {
  ushort8 v;
  #pragma unroll
  for (int j = 0; j < 8; ++j) v[j] = f2bf(w[j]);
  union { ushort8 u; bf16x8 b; } cv; cv.u = v; return cv.b;
}

// LDS: s_x [32 m][512 k] bf16 XOR-swizzled (32KB) + dispatch scratch
__global__ __launch_bounds__(256, 1) void hetenet_fused(
    const float* __restrict__ obs, const float* __restrict__ W1,
    const float* __restrict__ b1, const float* __restrict__ W2,
    const float* __restrict__ b2, const int* __restrict__ pick,
    float* __restrict__ out)
{
  __shared__ char s_xraw[32768];
  __shared__ int s_wt[4][16];     // wave expert totals
  __shared__ int s_we[4];         // wave totals for selected expert
  __shared__ int s_list[TILE_M];  // this tile's token ids
  char* s_x = s_xraw;

  const int tid = threadIdx.x, lane = tid & 63, wave = tid >> 6;
  const int l15 = lane & 15, l4 = lane >> 4;

  // ---- load pick: 16 tokens/thread (identical order to verified R12) ----
  int pk[16];
  {
    const int4* pv = (const int4*)pick + tid * 4;
    int4 q0 = pv[0], q1 = pv[1], q2 = pv[2], q3 = pv[3];
    pk[0]=q0.x; pk[1]=q0.y; pk[2]=q0.z; pk[3]=q0.w;
    pk[4]=q1.x; pk[5]=q1.y; pk[6]=q1.z; pk[7]=q1.w;
    pk[8]=q2.x; pk[9]=q2.y; pk[10]=q2.z; pk[11]=q2.w;
    pk[12]=q3.x; pk[13]=q3.y; pk[14]=q3.z; pk[15]=q3.w;
  }
  // ---- per-expert wave totals (butterfly) ----
  #pragma unroll
  for (int ee = 0; ee < NEXP; ++ee) {
    int v = 0;
    #pragma unroll
    for (int i = 0; i < 16; ++i) v += (pk[i] == ee) ? 1 : 0;
    #pragma unroll
    for (int off = 1; off < 64; off <<= 1) v += __shfl_xor(v, off, 64);
    if (lane == 0) s_wt[wave][ee] = v;
  }
  __syncthreads();
  // ---- block totals -> tile geometry; XCD-chunked bijective mapping ----
  int ntl[NEXP], ntiles = 0;
  #pragma unroll
  for (int ee = 0; ee < NEXP; ++ee) {
    int ct = s_wt[0][ee] + s_wt[1][ee] + s_wt[2][ee] + s_wt[3][ee];
    ntl[ee] = (ct + TILE_M - 1) >> 5;
    ntiles += ntl[ee];
  }
  const int p = blockIdx.x;
  const int xq = ntiles >> 3, xr = ntiles & 7;
  const int xcd = p & 7, slot = p >> 3;
  const int cx = xq + (xcd < xr ? 1 : 0);
  if (slot >= cx) return;
  const int jt = xcd * xq + (xcd < xr ? xcd : xr) + slot;   // logical tile
  // ---- flag-based cumulative walk (R12-verified) ----
  int e = 0, til = 0, cnte = 0, cum = 0, found = 0;
  #pragma unroll
  for (int ee = 0; ee < NEXP; ++ee) {
    if (!found && jt < cum + ntl[ee]) {
      e = ee; til = jt - cum;
      cnte = s_wt[0][ee] + s_wt[1][ee] + s_wt[2][ee] + s_wt[3][ee];
      found = 1;
    }
    cum += ntl[ee];
  }
  const int tile_lo = til * TILE_M;
  int mvalid = cnte - tile_lo; if (mvalid > TILE_M) mvalid = TILE_M;

  // ---- positional scan for expert e; fill s_list (R12-verified) ----
  {
    int ce = 0;
    #pragma unroll
    for (int i = 0; i < 16; ++i) ce += (pk[i] == e) ? 1 : 0;
    int inc = ce;
    #pragma unroll
    for (int off = 1; off < 64; off <<= 1) {
      int v = __shfl_up(inc, off, 64);
      if (lane >= off) inc += v;
    }
    if (lane == 63) s_we[wave] = inc;
    __syncthreads();
    int base0 = 0;
    #pragma unroll
    for (int w = 0; w < 4; ++w) if (w < wave) base0 += s_we[w];
    int pos = base0 + inc - ce;
    #pragma unroll
    for (int i = 0; i < 16; ++i) {
      if (pk[i] == e) {
        int rel = pos - tile_lo;
        if (rel >= 0 && rel < TILE_M) s_list[rel] = tid * 16 + i;
        pos++;
      }
    }
  }
  __syncthreads();

  const float* W1e = W1 + (size_t)e * (DDIM * HDIM);
  const float* W2e = W2 + (size_t)e * (HDIM * ADIM);
  const int nbase = wave * 128;     // this wave's 128 H-cols

  // ---- X gather: 32 rows x 8 threads, fp32 -> bf16 swizzled into s_x ----
  {
    const int m = tid >> 3, s8 = tid & 7;
    const float* grow = obs + (size_t)s_list[m < mvalid ? m : mvalid - 1] * DDIM;
    #pragma unroll
    for (int si = 0; si < 8; ++si) {
      int s = s8 + si * 8;
      float4 f0 = *(const float4*)(grow + s * 8);
      float4 f1 = *(const float4*)(grow + s * 8 + 4);
      ushort8 v;
      v[0] = f2bf(f0.x); v[1] = f2bf(f0.y); v[2] = f2bf(f0.z); v[3] = f2bf(f0.w);
      v[4] = f2bf(f1.x); v[5] = f2bf(f1.y); v[6] = f2bf(f1.z); v[7] = f2bf(f1.w);
      *(ushort8*)(s_x + m * 1024 + ((s ^ (m & 7)) << 4)) = v;
    }
  }
  __syncthreads();

  // ---- acc init = b1 bias (C1^T: row = n-local = l4*4+r, col = m = l15) ----
  f32x4 acc[8][2];
  #pragma unroll
  for (int nt = 0; nt < 8; ++nt) {
    float4 bv = *(const float4*)(b1 + e * HDIM + nbase + nt * 16 + l4 * 4);
    f32x4 b4 = {bv.x, bv.y, bv.z, bv.w};
    acc[nt][0] = b4; acc[nt][1] = b4;
  }

  // ---- GEMM1 (swapped): W1 fragments straight from fp32 global ----
  // wfr[nt] lane: n = nbase+nt*16+l15, k = t*32 + l4*8 + j, elem j = W1e[k*512+n]
  // (identical fragment layout to the verified LDS-image path)
  #pragma unroll
  for (int t = 0; t < 16; ++t) {
    const int k0 = t * 32 + l4 * 8;
    bf16x8 wfr[8], xfr[2];
    #pragma unroll
    for (int nt = 0; nt < 8; ++nt) {
      const float* wp = W1e + (size_t)k0 * HDIM + (nbase + nt * 16 + l15);
      float w[8];
      #pragma unroll
      for (int j = 0; j < 8; ++j) w[j] = wp[(size_t)j * HDIM];
      wfr[nt] = pack8(w);
    }
    #pragma unroll
    for (int mt = 0; mt < 2; ++mt) {
      int mm = mt * 16 + l15;
      xfr[mt] = *(const bf16x8*)(s_x + mm * 1024 + ((((t << 2) + l4) ^ (mm & 7)) << 4));
    }
    #pragma unroll
    for (int nt = 0; nt < 8; ++nt)
      #pragma unroll
      for (int mt = 0; mt < 2; ++mt)
        acc[nt][mt] = __builtin_amdgcn_mfma_f32_16x16x32_bf16(wfr[nt], xfr[mt], acc[nt][mt], 0, 0, 0);
  }

  __syncthreads();   // all waves finished reading X from s_x

  // ---- h = relu(acc + b1) -> bf16 into s_x (full H; verified R4 scheme) ----
  #pragma unroll
  for (int nt = 0; nt < 8; ++nt) {
    int n0 = nbase + nt * 16 + l4 * 4;
    int sg = n0 >> 3, hsel = (n0 >> 2) & 1;
    #pragma unroll
    for (int mt = 0; mt < 2; ++mt) {
      int mm = mt * 16 + l15;
      typedef __attribute__((ext_vector_type(4))) unsigned short ushort4v;
      ushort4v hv;
      #pragma unroll
      for (int r = 0; r < 4; ++r) hv[r] = f2bf(fmaxf(acc[nt][mt][r], 0.f));
      *(ushort4v*)(s_x + mm * 1024 + ((sg ^ (mm & 7)) << 4) + hsel * 8) = hv;
    }
  }
  __syncthreads();

  // ---- GEMM2: C2[32 m][32 a], K=512; wave quadrant (mt2, at2); W2 fp32 direct ----
  // bf lane: a = at2*16+l15, k = ks*32 + l4*8 + j, elem j = W2e[k*32+a]
  const int mt2 = wave >> 1, at2 = wave & 1;
  const int a2 = at2 * 16 + l15;
  const float b2v = b2[e * ADIM + a2];
  f32x4 acc2 = {b2v, b2v, b2v, b2v};
  #pragma unroll
  for (int ks = 0; ks < 16; ++ks) {
    const int k0 = ks * 32 + l4 * 8;
    int mm = mt2 * 16 + l15;
    bf16x8 af = *(const bf16x8*)(s_x + mm * 1024 + ((((ks << 2) + l4) ^ (mm & 7)) << 4));
    const float* wp = W2e + (size_t)k0 * ADIM + a2;
    float w[8];
    #pragma unroll
    for (int j = 0; j < 8; ++j) w[j] = wp[(size_t)j * ADIM];
    bf16x8 bf = pack8(w);
    acc2 = __builtin_amdgcn_mfma_f32_16x16x32_bf16(af, bf, acc2, 0, 0, 0);
  }
  // ---- epilogue: direct stores (full H in-block -> complete result, no atomics) ----
  #pragma unroll
  for (int r = 0; r < 4; ++r) {
    int mrow = mt2 * 16 + l4 * 4 + r;
    if (mrow < mvalid)
      out[(size_t)s_list[mrow] * ADIM + a2] = acc2[r];
  }
}

extern "C" void kernel_launch(void* const* d_in, const int* in_sizes, int n_in,
                              void* d_out, int out_size, void* d_ws, size_t ws_size,
                              hipStream_t stream)
{
  const float* obs = (const float*)d_in[0];
  const float* W1  = (const float*)d_in[1];
  const float* b1  = (const float*)d_in[2];
  const float* W2  = (const float*)d_in[3];
  const float* b2  = (const float*)d_in[4];
  const int* pick  = (const int*)d_in[5];
  float* out = (float*)d_out;
  (void)in_sizes; (void)n_in; (void)out_size; (void)d_ws; (void)ws_size;

  hetenet_fused<<<dim3(GRID_F), dim3(256), 0, stream>>>(
      obs, W1, b1, W2, b2, pick, out);
}

// Round 14
// 25.180 us; speedup vs baseline: 1.5145x; 1.5145x over previous
//
#include <hip/hip_runtime.h>
#include <stdint.h>

// HeteNet distribute_compute: T=64, N=64, D=512, H=512, A=32, E=15
#define NTOK 4096
#define DDIM 512
#define HDIM 512
#define ADIM 32
#define NEXP 15
#define TILE_M 32
#define GRID_M 288     // covers nphys = 2*ntiles <= 286, xcd-chunked

typedef __attribute__((ext_vector_type(8))) short bf16x8;
typedef __attribute__((ext_vector_type(8))) unsigned short ushort8;
typedef __attribute__((ext_vector_type(4))) unsigned short ushort4v;
typedef __attribute__((ext_vector_type(4))) float f32x4;

__device__ __forceinline__ unsigned short f2bf(float f) {
  unsigned int u = __float_as_uint(f);
  u += 0x7fffu + ((u >> 16) & 1u);   // round-to-nearest-even
  return (unsigned short)(u >> 16);
}

__device__ __forceinline__ void gld_lds16(const void* g, void* l) {
  __builtin_amdgcn_global_load_lds(
      (const __attribute__((address_space(1))) void*)g,
      (__attribute__((address_space(3))) void*)l, 16, 0, 0);
}

// ---------------- prep: 256 blocks, XCD-affine to moe's consumers ----------------
// Block p: x = p%8 (XCD), s = p/8 (slot 0..31).
//   x<7 : W1 image for expert e = 2x + (s>>4), chunk kc = s&15   (16 chunks/expert)
//   x==7: s<16 -> expert 14, kc = s; s in 16..30 -> W2T expert s-16 + zero out-slice;
//         s==31 -> token bucketing + tile table (wave-shuffle scan, deterministic).
// Expert e's image chunks all land on XCD floor(e/2) == moe's consumer XCD.
// W1 image chunk layout: [512 n][4 slot][16B], slot swizzle baked:
//   physical slot p holds k-sub q = p ^ ((n>>1)&3)
__global__ __launch_bounds__(256) void prep_kernel(
    const float* __restrict__ W1, const float* __restrict__ W2,
    const int* __restrict__ pick, int* __restrict__ meta,
    int* __restrict__ lists, unsigned short* __restrict__ W1I,
    unsigned short* __restrict__ W2T, float* __restrict__ out)
{
  extern __shared__ char smem[];
  const int bid = blockIdx.x;
  const int tid = threadIdx.x;
  const int x = bid & 7, s = bid >> 3;
  int role, e = 0, kc = 0;
  if (x < 7)       { role = 0; e = 2 * x + (s >> 4); kc = s & 15; }
  else if (s < 16) { role = 0; e = 14; kc = s; }
  else if (s < 31) { role = 1; e = s - 16; }
  else             { role = 2; }

  if (role == 0) {
    float* sm = (float*)smem;                      // [32][517] padded fp32
    const int r0 = kc * 32;
    const float* src = W1 + (size_t)e * (DDIM * HDIM) + (size_t)r0 * HDIM;
    #pragma unroll
    for (int v = 0; v < 16; ++v) {
      int i = v * 256 + tid;
      int row = i >> 7, col = (i & 127) * 4;
      *(float4*)(sm + row * 517 + col) = *(const float4*)(src + (size_t)row * 512 + col);
    }
    __syncthreads();
    unsigned short* dst = W1I + (size_t)(e * 16 + kc) * 512 * 32;
    const int p = tid & 3;
    #pragma unroll
    for (int w = 0; w < 8; ++w) {
      int n = w * 64 + (tid >> 2);
      int q = p ^ ((n >> 1) & 3);
      ushort8 vv;
      #pragma unroll
      for (int xx = 0; xx < 8; ++xx) vv[xx] = f2bf(sm[(q * 8 + xx) * 517 + n]);
      *(ushort8*)(dst + (size_t)n * 32 + p * 8) = vv;
    }
  } else if (role == 1) {
    // zero out[] slice (harness poisons 0xAA; moe epilogue uses atomicAdd)
    float4 z4; z4.x = 0.f; z4.y = 0.f; z4.z = 0.f; z4.w = 0.f;
    for (int i = e * 256 + tid; i < NTOK * ADIM / 4; i += 15 * 256)
      ((float4*)out)[i] = z4;
    float* sm = (float*)smem;                      // [512][36] padded fp32
    const float* src = W2 + (size_t)e * (HDIM * ADIM);
    #pragma unroll
    for (int v = 0; v < 16; ++v) {
      int i = v * 256 + tid;
      int row = i >> 3, col = (i & 7) * 4;
      *(float4*)(sm + row * 36 + col) = *(const float4*)(src + (size_t)row * 32 + col);
    }
    __syncthreads();
    unsigned short* dst = W2T + (size_t)e * (ADIM * HDIM);
    const int a = tid >> 3, k0 = (tid & 7) * 64;
    #pragma unroll
    for (int w = 0; w < 8; ++w) {
      ushort8 vv;
      #pragma unroll
      for (int xx = 0; xx < 8; ++xx) vv[xx] = f2bf(sm[(size_t)(k0 + w * 8 + xx) * 36 + a]);
      *(ushort8*)(dst + (size_t)a * 512 + k0 + w * 8) = vv;
    }
  } else {
    // deterministic bucketing via wave-shuffle scan ((tid,i) lexicographic order)
    int* s_pos = (int*)smem;            // [15][256] exclusive positions
    int* s_wt  = s_pos + NEXP * 256;    // [4][16] wave totals
    int* s_nt  = s_wt + 64;             // [16]
    int* s_bse = s_nt + 16;             // [16]
    const int lane = tid & 63, wv = tid >> 6;
    int pk[16];
    #pragma unroll
    for (int i = 0; i < 16; ++i) pk[i] = pick[tid * 16 + i];
    int c[NEXP], inc[NEXP];
    #pragma unroll
    for (int ee = 0; ee < NEXP; ++ee) {
      int cc = 0;
      #pragma unroll
      for (int i = 0; i < 16; ++i) cc += (pk[i] == ee) ? 1 : 0;
      c[ee] = cc; inc[ee] = cc;
    }
    #pragma unroll
    for (int off = 1; off < 64; off <<= 1) {
      #pragma unroll
      for (int ee = 0; ee < NEXP; ++ee) {
        int v = __shfl_up(inc[ee], off, 64);
        if (lane >= off) inc[ee] += v;
      }
    }
    if (lane == 63) {
      #pragma unroll
      for (int ee = 0; ee < NEXP; ++ee) s_wt[wv * 16 + ee] = inc[ee];
    }
    __syncthreads();
    #pragma unroll
    for (int ee = 0; ee < NEXP; ++ee) {
      int base0 = 0;
      #pragma unroll
      for (int w = 0; w < 4; ++w) if (w < wv) base0 += s_wt[w * 16 + ee];
      s_pos[ee * 256 + tid] = base0 + inc[ee] - c[ee];
    }
    #pragma unroll
    for (int i = 0; i < 16; ++i) {
      int pp = pk[i];
      int pos = s_pos[pp * 256 + tid]++;
      lists[pp * NTOK + pos] = tid * 16 + i;
    }
    if (tid < NEXP) {
      int tot = s_wt[tid] + s_wt[16 + tid] + s_wt[32 + tid] + s_wt[48 + tid];
      meta[tid] = tot;
      s_nt[tid] = (tot + TILE_M - 1) / TILE_M;
    }
    __syncthreads();
    if (tid == 0) {
      int b = 0;
      for (int ee = 0; ee < NEXP; ++ee) { s_bse[ee] = b; b += s_nt[ee]; }
      meta[15] = b;
    }
    __syncthreads();
    if (tid < NEXP) {
      int b = s_bse[tid], nt2 = s_nt[tid];
      for (int i = 0; i < nt2; ++i) meta[16 + b + i] = (tid << 16) | i;
    }
  }
}

// ---------------- fused grouped MLP: 32-token tile x H-half, 2 blocks/CU ----------------
// LDS 80KB -> 2 blocks/CU. s_x [32 m][512 k] bf16 swizzled (32KB); wb0/1/2 16KB.
// GEMM1 K=512 full -> h complete in-block. GEMM2 K=256 partial -> fp32 atomicAdd.
// Barrier-free K loop: wave stages+reads only its own 64 W rows; counted vmcnt.
__global__ __launch_bounds__(256, 2) void moe_gemm(
    const float* __restrict__ obs, const float* __restrict__ b1,
    const float* __restrict__ b2, const int* __restrict__ meta,
    const int* __restrict__ lists, const unsigned short* __restrict__ W1I,
    const unsigned short* __restrict__ W2T, float* __restrict__ out)
{
  const int ntiles = meta[15];
  const int nphys = ntiles * 2;
  const int p = blockIdx.x;
  const int xq = nphys >> 3, xr = nphys & 7;
  const int xcd = p & 7, slot = p >> 3;
  const int cx = xq + (xcd < xr ? 1 : 0);
  if (slot >= cx) return;
  const int j2 = xcd * xq + (xcd < xr ? xcd : xr) + slot;  // bijective; pair same-XCD
  const int jt = j2 >> 1, half = j2 & 1;

  const int tl = meta[16 + jt];
  const int e = tl >> 16;
  const int tile_lo = (tl & 0xffff) * TILE_M;
  const int cnt = meta[e];
  int mvalid = cnt - tile_lo; if (mvalid > TILE_M) mvalid = TILE_M;

  extern __shared__ char smem[];
  char* s_x = smem;            // 32KB
  char* wb0 = smem + 32768;    // 16KB
  char* wb1 = smem + 49152;    // 16KB
  char* wb2 = smem + 65536;    // 16KB

  const int tid = threadIdx.x, lane = tid & 63, wave = tid >> 6;
  const int l15 = lane & 15, l4 = lane >> 4;
  const int nbl = wave * 64;        // block-local n slice for this wave (64 rows)
  const int hbase = half * 256;     // global-H base of this block
  const int* mylist = lists + e * NTOK;
  const unsigned short* w1i_e = W1I + (size_t)e * 16 * 512 * 32;
  const unsigned short* w2t_e = W2T + (size_t)e * (ADIM * HDIM);

  // ---- issue X gather FIRST (oldest in queue) ----
  const int m = tid >> 3, s8 = tid & 7;
  int idx = tile_lo + m; if (idx >= cnt) idx = cnt - 1;
  const float* grow = obs + (size_t)mylist[idx] * DDIM;
  float4 xf[16];
  #pragma unroll
  for (int si = 0; si < 8; ++si) {
    xf[si * 2]     = *(const float4*)(grow + (s8 + si * 8) * 8);
    xf[si * 2 + 1] = *(const float4*)(grow + (s8 + si * 8) * 8 + 4);
  }
  __builtin_amdgcn_sched_barrier(0);

  // ---- b1 bias loads BEFORE W1 issues ----
  float4 bvv[4];
  #pragma unroll
  for (int nt = 0; nt < 4; ++nt)
    bvv[nt] = *(const float4*)(b1 + e * HDIM + hbase + nbl + nt * 16 + l4 * 4);
  __builtin_amdgcn_sched_barrier(0);

  // ---- issue W1 chunks 0,1 (async -> LDS, per-wave own rows); ordered groups ----
  auto issue_w1 = [&](int t, char* buf) {
    const unsigned short* wbase = w1i_e + (size_t)t * (512 * 32) + (size_t)hbase * 32;
    #pragma unroll
    for (int i = 0; i < 4; ++i) {
      int nb = nbl + i * 16;
      gld_lds16(wbase + (size_t)nb * 32 + lane * 8, buf + nb * 64);
    }
  };
  issue_w1(0, wb0);
  __builtin_amdgcn_sched_barrier(0);
  issue_w1(1, wb1);
  __builtin_amdgcn_sched_barrier(0);

  // ---- convert + store X to LDS (consuming xf waits only on X loads) ----
  #pragma unroll
  for (int si = 0; si < 8; ++si) {
    int s = s8 + si * 8;
    float4 f0 = xf[si * 2], f1 = xf[si * 2 + 1];
    ushort8 v;
    v[0] = f2bf(f0.x); v[1] = f2bf(f0.y); v[2] = f2bf(f0.z); v[3] = f2bf(f0.w);
    v[4] = f2bf(f1.x); v[5] = f2bf(f1.y); v[6] = f2bf(f1.z); v[7] = f2bf(f1.w);
    *(ushort8*)(s_x + m * 1024 + ((s ^ (m & 7)) << 4)) = v;
  }
  __syncthreads();

  // ---- acc init = b1 bias (C1^T: row=n, col=m) ----
  f32x4 acc[4][2];
  #pragma unroll
  for (int nt = 0; nt < 4; ++nt) {
    f32x4 b4 = {bvv[nt].x, bvv[nt].y, bvv[nt].z, bvv[nt].w};
    acc[nt][0] = b4; acc[nt][1] = b4;
  }

  // ---- GEMM1 (swapped): acc[nt][mt] += W1frag x Xfrag; barrier-free, counted vmcnt ----
  #pragma unroll
  for (int t = 0; t < 16; ++t) {
    if (t < 14) {
      char* nxt = ((t + 2) % 3 == 0) ? wb0 : ((t + 2) % 3 == 1) ? wb1 : wb2;
      issue_w1(t + 2, nxt);
    } else if (t == 14) {
      // stage W2 k-half -> wb1 (free after t=13); pre-swizzled source
      #pragma unroll
      for (int i = 0; i < 4; ++i) {
        int o = wave * 4096 + i * 1024 + lane * 16;   // byte offset in wb1
        int a = o >> 9;                               // 0..31 (512B per a-row)
        int p16 = (o >> 4) & 31;                      // 16B slot in row
        gld_lds16(w2t_e + (size_t)a * 512 + hbase + (size_t)((p16 ^ (a & 7)) * 8),
                  wb1 + o);
      }
    }
    if (t < 15) asm volatile("s_waitcnt vmcnt(8)" ::: "memory");
    else        asm volatile("s_waitcnt vmcnt(4)" ::: "memory");
    __builtin_amdgcn_sched_barrier(0);

    const char* cw = (t % 3 == 0) ? wb0 : (t % 3 == 1) ? wb1 : wb2;
    bf16x8 wfr[4], xfr[2];
    #pragma unroll
    for (int nt = 0; nt < 4; ++nt) {
      int n = nbl + nt * 16 + l15;
      wfr[nt] = *(const bf16x8*)(cw + n * 64 + ((l4 ^ ((n >> 1) & 3)) << 4));
    }
    #pragma unroll
    for (int mt = 0; mt < 2; ++mt) {
      int mm = mt * 16 + l15;
      xfr[mt] = *(const bf16x8*)(s_x + mm * 1024 + ((((t << 2) + l4) ^ (mm & 7)) << 4));
    }
    #pragma unroll
    for (int nt = 0; nt < 4; ++nt)
      #pragma unroll
      for (int mt = 0; mt < 2; ++mt)
        acc[nt][mt] = __builtin_amdgcn_mfma_f32_16x16x32_bf16(wfr[nt], xfr[mt], acc[nt][mt], 0, 0, 0);
  }

  __syncthreads();   // all waves finished reading s_x

  // ---- h = relu(acc) -> bf16 into s_x (block-local k = 0..256) ----
  #pragma unroll
  for (int nt = 0; nt < 4; ++nt) {
    int n0 = nbl + nt * 16 + l4 * 4;          // block-local h index
    int sg = n0 >> 3, hsel = (n0 >> 2) & 1;
    #pragma unroll
    for (int mt = 0; mt < 2; ++mt) {
      int mm = mt * 16 + l15;
      ushort4v hv;
      #pragma unroll
      for (int r = 0; r < 4; ++r) hv[r] = f2bf(fmaxf(acc[nt][mt][r], 0.f));
      *(ushort4v*)(s_x + mm * 1024 + ((sg ^ (mm & 7)) << 4) + hsel * 8) = hv;
    }
  }
  __syncthreads();   // h complete; W2 drained by barrier's vmcnt(0)

  // ---- GEMM2 partial: C2[32 m][32 a] over K=256; wave quadrant (mt2, at2) ----
  const int mt2 = wave >> 1, at2 = wave & 1;
  const int a2 = at2 * 16 + l15;
  float b2v = half ? 0.f : b2[e * ADIM + a2];
  f32x4 acc2 = {b2v, b2v, b2v, b2v};
  #pragma unroll
  for (int ks = 0; ks < 8; ++ks) {
    int mm = mt2 * 16 + l15;
    bf16x8 af = *(const bf16x8*)(s_x + mm * 1024 + ((((ks << 2) + l4) ^ (mm & 7)) << 4));
    bf16x8 bf = *(const bf16x8*)(wb1 + a2 * 512 + ((((ks << 2) + l4) ^ (a2 & 7)) << 4));
    acc2 = __builtin_amdgcn_mfma_f32_16x16x32_bf16(af, bf, acc2, 0, 0, 0);
  }
  // ---- epilogue: combine the two H-halves via atomicAdd (deterministic 2-way) ----
  #pragma unroll
  for (int r = 0; r < 4; ++r) {
    int mrow = mt2 * 16 + l4 * 4 + r;
    if (mrow < mvalid)
      atomicAdd(&out[(size_t)mylist[tile_lo + mrow] * ADIM + a2], acc2[r]);
  }
}

// ---------------- fallback (ws too small): fp32, block per token ----------------
__global__ __launch_bounds__(256) void naive_kernel(
    const float* __restrict__ obs, const float* __restrict__ W1,
    const float* __restrict__ b1, const float* __restrict__ W2,
    const float* __restrict__ b2, const int* __restrict__ pick,
    float* __restrict__ out)
{
  __shared__ float sx[DDIM];
  __shared__ float sh[HDIM];
  const int t = blockIdx.x, tid = threadIdx.x;
  const int e = pick[t];
  const float* x = obs + (size_t)t * DDIM;
  for (int i = tid; i < DDIM; i += 256) sx[i] = x[i];
  __syncthreads();
  const float* w1 = W1 + (size_t)e * DDIM * HDIM;
  for (int j = tid; j < HDIM; j += 256) {
    float a = b1[e * HDIM + j];
    for (int d = 0; d < DDIM; ++d) a = fmaf(sx[d], w1[(size_t)d * HDIM + j], a);
    sh[j] = a > 0.f ? a : 0.f;
  }
  __syncthreads();
  if (tid < ADIM) {
    const float* w2 = W2 + (size_t)e * HDIM * ADIM;
    float a = b2[e * ADIM + tid];
    for (int j = 0; j < HDIM; ++j) a = fmaf(sh[j], w2[(size_t)j * ADIM + tid], a);
    out[(size_t)t * ADIM + tid] = a;
  }
}

extern "C" void kernel_launch(void* const* d_in, const int* in_sizes, int n_in,
                              void* d_out, int out_size, void* d_ws, size_t ws_size,
                              hipStream_t stream)
{
  const float* obs = (const float*)d_in[0];
  const float* W1  = (const float*)d_in[1];
  const float* b1  = (const float*)d_in[2];
  const float* W2  = (const float*)d_in[3];
  const float* b2  = (const float*)d_in[4];
  const int* pick  = (const int*)d_in[5];
  float* out = (float*)d_out;
  (void)in_sizes; (void)n_in; (void)out_size;

  const size_t OFF_LISTS = 1024;
  const size_t OFF_W1I   = 262144;                                   // 256KB
  const size_t OFF_W2T   = OFF_W1I + (size_t)NEXP * HDIM * DDIM * 2; // +7.5MB
  const size_t WS_NEEDED = OFF_W2T + (size_t)NEXP * ADIM * HDIM * 2; // ~8.6MB

  if (ws_size < WS_NEEDED) {
    naive_kernel<<<dim3(NTOK), dim3(256), 0, stream>>>(obs, W1, b1, W2, b2, pick, out);
    return;
  }

  char* ws = (char*)d_ws;
  int* meta   = (int*)ws;                  // [0..14] counts, [15] ntiles, [16..] tiles
  int* lists  = (int*)(ws + OFF_LISTS);
  unsigned short* W1I = (unsigned short*)(ws + OFF_W1I);
  unsigned short* W2T = (unsigned short*)(ws + OFF_W2T);

  prep_kernel<<<dim3(256), dim3(256), 73728, stream>>>(
      W1, W2, pick, meta, lists, W1I, W2T, out);
  moe_gemm<<<dim3(GRID_M), dim3(256), 81920, stream>>>(
      obs, b1, b2, meta, lists, W1I, W2T, out);
}